// Round 11
// baseline (286.179 us; speedup 1.0000x reference)
//
#include <hip/hip_runtime.h>

typedef float v2f __attribute__((ext_vector_type(2)));

constexpr int NX = 192, NY = 192, NZ = 192, NB = 2;
constexpr int ZPT  = 4;              // z outputs per thread
constexpr int YL   = 16;             // lanes per DPP row = staged y-rows
constexpr int YOUT = 14;             // valid outputs per y-group (lanes 1..14)
constexpr int ZC   = 12;             // z-chunks per block
constexpr int ZSPAN = ZC * ZPT;      // 48
constexpr int XSEG = 4;              // x outputs per block
constexpr int BLOCK_THREADS = YL * ZC;   // 192 = 3 waves
constexpr int PLANE = NY * NZ;
constexpr int NXT = NX / XSEG;                    // 48
constexpr int NYT = (NY + YOUT - 1) / YOUT;       // 14
constexpr int NZT = NZ / ZSPAN;                   // 4
constexpr int NBLK = NXT * NYT * NZT * NB;        // 5376

constexpr int ZS_F  = 56;            // staged z floats per row: [Z0-4, Z0+52)
constexpr int RSTR  = 60;            // row stride (56 + 4 pad: rotates bank starts)
constexpr int NROW  = YL;            // 16 rows per tensor
constexpr int TILE_F = 2 * NROW * RSTR;          // 1920 floats = 7680 B per buffer
constexpr int SUNITS = 2 * NROW * (ZS_F / 4);    // 448 float4 staging units

// lane n <- lane n-1 within 16-lane DPP row (0-filled at row edge)
__device__ __forceinline__ float dpp_shr1(float v) {
    return __int_as_float(__builtin_amdgcn_update_dpp(
        0, __float_as_int(v), 0x111, 0xf, 0xf, true));
}
// lane n <- lane n+1
__device__ __forceinline__ float dpp_shl1(float v) {
    return __int_as_float(__builtin_amdgcn_update_dpp(
        0, __float_as_int(v), 0x101, 0xf, 0xf, true));
}
__device__ __forceinline__ float dpp_sum3(float v) {   // v(y-1)+v(y)+v(y+1)
    return v + dpp_shr1(v) + dpp_shl1(v);
}

// ---- spill-proof value types: no arrays, no interior pointers ----
struct W2  { v2f lo, hi; };
struct Acc { W2 t, p, t2, p2, tp; };

__device__ __forceinline__ W2 addW(W2 a, W2 b) { return { a.lo + b.lo, a.hi + b.hi }; }
__device__ __forceinline__ Acc addA(const Acc& a, const Acc& b) {
    return { addW(a.t, b.t), addW(a.p, b.p), addW(a.t2, b.t2),
             addW(a.p2, b.p2), addW(a.tp, b.tp) };
}

// z-fold (6 taps -> 4 windows) then DPP y-fold; returns by value
__device__ __forceinline__ W2 zfold_dpp(v2f a, v2f b, v2f c) {
    const float s0 = a.x, s1 = a.y, s2 = b.x, s3 = b.y, s4 = c.x, s5 = c.y;
    const float m12 = s1 + s2, m34 = s3 + s4;
    W2 w;
    w.lo = v2f{ dpp_sum3(s0 + m12), dpp_sum3(m12 + s3) };
    w.hi = v2f{ dpp_sum3(s2 + m34), dpp_sum3(m34 + s5) };
    return w;
}

// Fold one staged x-plane: own-row loads -> products -> z-fold -> DPP y-fold.
template<bool SAFE>
__device__ __forceinline__ Acc foldPlane(const float* __restrict__ buf,
    int rowt, int rowp, int zi, float wzm, float wze, float wyow)
{
    const float4 t4 = *reinterpret_cast<const float4*>(buf + rowt + zi);
    const float4 p4 = *reinterpret_cast<const float4*>(buf + rowp + zi);
    const float tm = buf[rowt + zi - 1] * wzm, te = buf[rowt + zi + 4] * wze;
    const float pm = buf[rowp + zi - 1] * wzm, pe = buf[rowp + zi + 4] * wze;
    v2f T0 = v2f{tm, t4.x}, T1 = v2f{t4.y, t4.z}, T2 = v2f{t4.w, te};
    v2f P0 = v2f{pm, p4.x}, P1 = v2f{p4.y, p4.z}, P2 = v2f{p4.w, pe};
    if (!SAFE) {   // wyow in {0,1}: exact masking of OOB x-plane / y-row
        T0 *= wyow; T1 *= wyow; T2 *= wyow;
        P0 *= wyow; P1 *= wyow; P2 *= wyow;
    }
    Acc a;
    a.t  = zfold_dpp(T0,      T1,      T2);
    a.p  = zfold_dpp(P0,      P1,      P2);
    a.t2 = zfold_dpp(T0 * T0, T1 * T1, T2 * T2);
    a.p2 = zfold_dpp(P0 * P0, P1 * P1, P2 * P2);
    a.tp = zfold_dpp(T0 * P0, T1 * P1, T2 * P2);
    return a;
}

// NCC for 4 z-outputs given full 27-voxel window sums
__device__ __forceinline__ float epilogue4(const Acc& s)
{
    constexpr float inv_vol = 1.0f / 27.0f;
    float acc = 0.f;
    #pragma unroll
    for (int h = 0; h < 2; ++h) {
        const v2f st  = h ? s.t.hi  : s.t.lo;
        const v2f sp  = h ? s.p.hi  : s.p.lo;
        const v2f st2 = h ? s.t2.hi : s.t2.lo;
        const v2f sp2 = h ? s.p2.hi : s.p2.lo;
        const v2f stp = h ? s.tp.hi : s.tp.lo;
        const v2f tavg = st * inv_vol;
        const v2f pavg = sp * inv_vol;
        const v2f cross = stp - pavg * st;
        const v2f tvp   = st2 - tavg * st;
        const v2f pvp   = sp2 - pavg * sp;
        const v2f cc    = cross * cross;
        #pragma unroll
        for (int c = 0; c < 2; ++c) {
            const float tvar = fmaxf(tvp[c], 0.f);
            const float pvar = fmaxf(pvp[c], 0.f);
            acc += cc[c] * __builtin_amdgcn_rcpf(fmaf(tvar, pvar, 1e-5f));
        }
    }
    return acc;
}

template<bool SAFE>
__device__ __forceinline__ float march(
    const float* sb0, const float* sb1, const float* sb2, bool do3,
    int lo0, int lo1, int lo2, float (*tile)[TILE_F],
    int rowt, int rowp, int zi, float wzm, float wze, float wy, int xs0)
{
    Acc U, V, P;
    float acc = 0.f;
    float4 G0, G1, G2;

#define XOFF(K) (SAFE ? (xs0 - 1 + (K)) * PLANE \
                      : min(max(xs0 - 1 + (K), 0), NX - 1) * PLANE)
#define WXK(K)  (SAFE ? 1.f : wy * (((unsigned)(xs0 - 1 + (K)) < (unsigned)NX) ? 1.f : 0.f))
#define GLOAD(K) do { const int _xo = XOFF(K);                                  \
        G0 = *reinterpret_cast<const float4*>(sb0 + _xo);                       \
        G1 = *reinterpret_cast<const float4*>(sb1 + _xo);                       \
        if (do3) G2 = *reinterpret_cast<const float4*>(sb2 + _xo); } while (0)
#define DSWR(K) do { float* _d = tile[(K) & 1];                                 \
        *reinterpret_cast<float4*>(_d + lo0) = G0;                              \
        *reinterpret_cast<float4*>(_d + lo1) = G1;                              \
        if (do3) *reinterpret_cast<float4*>(_d + lo2) = G2; } while (0)
#define FOLD(K) foldPlane<SAFE>(tile[(K) & 1], rowt, rowp, zi, wzm, wze, WXK(K))

    GLOAD(0); DSWR(0); __syncthreads();
    GLOAD(1); U = FOLD(0);                    DSWR(1); __syncthreads();
    GLOAD(2); V = FOLD(1); P = addA(U, V);    DSWR(2); __syncthreads();
    GLOAD(3); U = FOLD(2); acc += epilogue4(addA(P, U)); P = addA(V, U); DSWR(3); __syncthreads();
    GLOAD(4); V = FOLD(3); acc += epilogue4(addA(P, V)); P = addA(U, V); DSWR(4); __syncthreads();
    GLOAD(5); U = FOLD(4); acc += epilogue4(addA(P, U)); P = addA(V, U); DSWR(5); __syncthreads();
              V = FOLD(5); acc += epilogue4(addA(P, V));

#undef XOFF
#undef WXK
#undef GLOAD
#undef DSWR
#undef FOLD
    return acc;
}

__global__ __launch_bounds__(BLOCK_THREADS, 3)
void ncc_partial(const float* __restrict__ pred, const float* __restrict__ label,
                 float* __restrict__ partials)
{
    __shared__ alignas(16) float tile[2][TILE_F];    // 15,360 B

    const int y   = threadIdx.x;                     // 0..15: y-lane in DPP row
    const int zc  = threadIdx.y;                     // 0..11: z-chunk
    const int tid = y + zc * YL;
    const int ytile = blockIdx.x % NYT;
    const int ztile = blockIdx.x / NYT;
    const int xs0 = blockIdx.y * XSEG;
    const int b   = blockIdx.z;
    const int Y0  = ytile * YOUT;
    const int Z0  = ztile * ZSPAN;
    const int bbase = b * (NX * PLANE);

    // staging: 448 float4 units = [tensor 2][row 16][z4 14]; thread does <=3
    const float* sb0; const float* sb1; const float* sb2;
    int lo0, lo1, lo2;
    {
        const float* sbv[3]; int lov[3];
        #pragma unroll
        for (int k = 0; k < 3; ++k) {
            const int u  = tid + k * BLOCK_THREADS;
            const int uu = (u < SUNITS) ? u : 0;
            const int tt  = uu / 224;
            const int rem = uu - tt * 224;
            const int row = rem / 14;
            const int c4  = rem - row * 14;
            const int grow = min(max(Y0 - 1 + row, 0), NY - 1);
            const int gz   = min(max(Z0 - 4 + 4 * c4, 0), NZ - 4);
            sbv[k] = (tt ? pred : label) + bbase + grow * NZ + gz;
            lov[k] = (tt * NROW + row) * RSTR + 4 * c4;
        }
        sb0 = sbv[0]; sb1 = sbv[1]; sb2 = sbv[2];
        lo0 = lov[0]; lo1 = lov[1]; lo2 = lov[2];
    }
    const bool do3 = (tid < SUNITS - 2 * BLOCK_THREADS);   // tid < 64 (wave-uniform)

    const int rowt = y * RSTR;
    const int rowp = (NROW + y) * RSTR;
    const int zi   = 4 + 4 * zc;                 // own float4 within staged row
    const int z0g  = Z0 + 4 * zc;
    const float wzm = (z0g > 0)      ? 1.f : 0.f;
    const float wze = (z0g + 4 < NZ) ? 1.f : 0.f;

    const int   prow = Y0 - 1 + y;               // own product row == own output row
    const float wy   = ((unsigned)prow < (unsigned)NY) ? 1.f : 0.f;

    const bool safe = (blockIdx.y >= 1) && (blockIdx.y <= NXT - 2) &&
                      (ytile >= 1) && (ytile <= NYT - 2);

    float acc = safe
        ? march<true >(sb0, sb1, sb2, do3, lo0, lo1, lo2, tile,
                       rowt, rowp, zi, wzm, wze, wy, xs0)
        : march<false>(sb0, sb1, sb2, do3, lo0, lo1, lo2, tile,
                       rowt, rowp, zi, wzm, wze, wy, xs0);

    // halo lanes (y=0,15) and OOB rows produce no output
    const float vout = (y >= 1 && y <= YOUT && prow < NY) ? 1.f : 0.f;
    acc *= vout;

    // wave (64) reduction, then block sum
    #pragma unroll
    for (int o = 32; o > 0; o >>= 1)
        acc += __shfl_down(acc, o, 64);

    __shared__ float wsum[BLOCK_THREADS / 64];
    if ((tid & 63) == 0) wsum[tid >> 6] = acc;
    __syncthreads();
    if (tid == 0) {
        float s = 0.f;
        #pragma unroll
        for (int w = 0; w < BLOCK_THREADS / 64; ++w) s += wsum[w];
        partials[blockIdx.x + (int)gridDim.x * (blockIdx.y + (int)gridDim.y * blockIdx.z)] = s;
    }
}

__global__ __launch_bounds__(256)
void ncc_reduce(const float* __restrict__ partials, int n, float* __restrict__ out)
{
    __shared__ double sh[256];
    double s = 0.0;
    for (int i = threadIdx.x; i < n; i += 256) s += (double)partials[i];
    sh[threadIdx.x] = s;
    __syncthreads();
    for (int off = 128; off > 0; off >>= 1) {
        if ((int)threadIdx.x < off) sh[threadIdx.x] += sh[threadIdx.x + off];
        __syncthreads();
    }
    if (threadIdx.x == 0) {
        const double nvox = (double)NB * NX * NY * NZ;
        out[0] = (float)(-sh[0] / nvox);
    }
}

extern "C" void kernel_launch(void* const* d_in, const int* in_sizes, int n_in,
                              void* d_out, int out_size, void* d_ws, size_t ws_size,
                              hipStream_t stream) {
    const float* pred  = (const float*)d_in[0];
    const float* label = (const float*)d_in[1];
    float* out = (float*)d_out;
    float* partials = (float*)d_ws;

    dim3 block(YL, ZC, 1);                       // 16 x 12 = 192 threads
    dim3 grid(NYT * NZT, NXT, NB);               // 56 x 48 x 2 = 5376 blocks

    ncc_partial<<<grid, block, 0, stream>>>(pred, label, partials);
    ncc_reduce<<<1, 256, 0, stream>>>(partials, NBLK, out);
}

// Round 12
// 110.502 us; speedup vs baseline: 2.5898x; 2.5898x over previous
//
#include <hip/hip_runtime.h>

typedef float v2f __attribute__((ext_vector_type(2)));

constexpr int NX = 192, NY = 192, NZ = 192, NB = 2;
constexpr int ZPT  = 4;            // z outputs per thread
constexpr int TZ   = NZ / ZPT;     // 48
constexpr int BY   = 4;            // y rows per block
constexpr int XSEG = 8;            // x outputs per block
constexpr int BLOCK_THREADS = TZ * BY;   // 192 = 3 waves
constexpr int PLANE = NY * NZ;
constexpr int NXB = NX / XSEG;     // 24
constexpr int NYB = NY / BY;       // 48
constexpr int NBLK = NYB * NXB * NB;     // 2304 blocks
constexpr int TILE_F = 2 * 6 * NZ;       // 2304 floats per LDS buffer

// Fold one staged x-plane from LDS (R8-proven structure).
template<bool SAFE>
__device__ __forceinline__ void foldLDS(const float* __restrict__ buf,
    int ty, int z0, const float wy[3], int dm, int de, float wzm, float wze,
    float wx, v2f W[5][2])
{
    v2f S[5][3];
    #pragma unroll
    for (int r = 0; r < 3; ++r) {
        const float* Lt = buf + (ty + r) * NZ;          // label row
        const float* Lp = Lt + 6 * NZ;                  // pred row
        const float4 t4 = *reinterpret_cast<const float4*>(Lt + z0);
        const float4 p4 = *reinterpret_cast<const float4*>(Lp + z0);
        const float tm = Lt[z0 - dm] * wzm, te = Lt[z0 + de] * wze;
        const float pm = Lp[z0 - dm] * wzm, pe = Lp[z0 + de] * wze;
        v2f T[3]  = { v2f{tm, t4.x}, v2f{t4.y, t4.z}, v2f{t4.w, te} };
        v2f Pv[3] = { v2f{pm, p4.x}, v2f{p4.y, p4.z}, v2f{p4.w, pe} };
        if (!SAFE) {
            const float wr = wx * wy[r];                // w in {0,1} => exact
            #pragma unroll
            for (int q = 0; q < 3; ++q) { T[q] *= wr; Pv[q] *= wr; }
        }
        #pragma unroll
        for (int q = 0; q < 3; ++q) {
            if (r == 0) {
                S[0][q] = T[q];  S[1][q] = Pv[q];
                S[2][q] = T[q] * T[q];  S[3][q] = Pv[q] * Pv[q];  S[4][q] = T[q] * Pv[q];
            } else {
                S[0][q] += T[q];  S[1][q] += Pv[q];
                S[2][q] += T[q] * T[q];  S[3][q] += Pv[q] * Pv[q];  S[4][q] += T[q] * Pv[q];
            }
        }
    }
    #pragma unroll
    for (int q = 0; q < 5; ++q) {
        const float s0 = S[q][0].x, s1 = S[q][0].y, s2 = S[q][1].x;
        const float s3 = S[q][1].y, s4 = S[q][2].x, s5 = S[q][2].y;
        const float m12 = s1 + s2, m34 = s3 + s4;
        W[q][0] = v2f{s0 + m12, m12 + s3};
        W[q][1] = v2f{s2 + m34, m34 + s5};
    }
}

__device__ __forceinline__ float epilogue4(const v2f P[5][2], const v2f Wn[5][2])
{
    constexpr float inv_vol = 1.0f / 27.0f;
    float acc = 0.f;
    #pragma unroll
    for (int h = 0; h < 2; ++h) {
        const v2f st  = P[0][h] + Wn[0][h];
        const v2f sp  = P[1][h] + Wn[1][h];
        const v2f st2 = P[2][h] + Wn[2][h];
        const v2f sp2 = P[3][h] + Wn[3][h];
        const v2f stp = P[4][h] + Wn[4][h];
        const v2f tavg = st * inv_vol;
        const v2f pavg = sp * inv_vol;
        const v2f cross = stp - pavg * st;
        const v2f tvp   = st2 - tavg * st;
        const v2f pvp   = sp2 - pavg * sp;
        const v2f cc    = cross * cross;
        #pragma unroll
        for (int c = 0; c < 2; ++c) {
            const float tvar = fmaxf(tvp[c], 0.f);
            const float pvar = fmaxf(pvp[c], 0.f);
            acc += cc[c] * __builtin_amdgcn_rcpf(fmaf(tvar, pvar, 1e-5f));
        }
    }
    return acc;
}

// March over XSEG+2 = 10 x-planes with double-buffered LDS staging.
// Per step: issue next plane's 3 float4 global loads -> fold current plane
// from LDS -> ds_write the loaded plane -> barrier.
template<bool SAFE>
__device__ __forceinline__ float march(
    const float* sb0, const float* sb1, const float* sb2,   // staging srcs (sans x)
    int lo0, int lo1, int lo2,                              // LDS float offsets
    float (*tile)[TILE_F],
    int ty, int z0, const float wy[3],
    int dm, int de, float wzm, float wze, int xs0)
{
    v2f U[5][2], V[5][2], P[5][2];
    float acc = 0.f;
    float4 G0, G1, G2;

#define XOFF(K) (SAFE ? (xs0 - 1 + (K)) * PLANE \
                      : min(max(xs0 - 1 + (K), 0), NX - 1) * PLANE)
#define WXK(K)  (SAFE ? 1.f : (((unsigned)(xs0 - 1 + (K)) < (unsigned)NX) ? 1.f : 0.f))
#define GLOAD(K) do { const int _xo = XOFF(K);                                  \
        G0 = *reinterpret_cast<const float4*>(sb0 + _xo);                       \
        G1 = *reinterpret_cast<const float4*>(sb1 + _xo);                       \
        G2 = *reinterpret_cast<const float4*>(sb2 + _xo); } while (0)
#define DSWR(K) do { float* _d = tile[(K) & 1];                                 \
        *reinterpret_cast<float4*>(_d + lo0) = G0;                              \
        *reinterpret_cast<float4*>(_d + lo1) = G1;                              \
        *reinterpret_cast<float4*>(_d + lo2) = G2; } while (0)
#define FOLD(K, WDST) foldLDS<SAFE>(tile[(K) & 1], ty, z0, wy, dm, de, wzm, wze, WXK(K), WDST)
#define PSET(A, B) do { _Pragma("unroll")                                       \
        for (int q = 0; q < 5; ++q) { _Pragma("unroll")                         \
            for (int h = 0; h < 2; ++h) P[q][h] = A[q][h] + B[q][h]; } } while (0)

    // prologue
    GLOAD(0); DSWR(0); __syncthreads();
    GLOAD(1); FOLD(0, U);             DSWR(1); __syncthreads();
    GLOAD(2); FOLD(1, V); PSET(U, V); DSWR(2); __syncthreads();
    // steady state: fold plane k, emit output xs0+k-2
    GLOAD(3); FOLD(2, U); acc += epilogue4(P, U); PSET(V, U); DSWR(3); __syncthreads();
    GLOAD(4); FOLD(3, V); acc += epilogue4(P, V); PSET(U, V); DSWR(4); __syncthreads();
    GLOAD(5); FOLD(4, U); acc += epilogue4(P, U); PSET(V, U); DSWR(5); __syncthreads();
    GLOAD(6); FOLD(5, V); acc += epilogue4(P, V); PSET(U, V); DSWR(6); __syncthreads();
    GLOAD(7); FOLD(6, U); acc += epilogue4(P, U); PSET(V, U); DSWR(7); __syncthreads();
    GLOAD(8); FOLD(7, V); acc += epilogue4(P, V); PSET(U, V); DSWR(8); __syncthreads();
    GLOAD(9); FOLD(8, U); acc += epilogue4(P, U); PSET(V, U); DSWR(9); __syncthreads();
              FOLD(9, V); acc += epilogue4(P, V);

#undef XOFF
#undef WXK
#undef GLOAD
#undef DSWR
#undef FOLD
#undef PSET
    return acc;
}

__global__ __launch_bounds__(BLOCK_THREADS, 3)
void ncc_partial(const float* __restrict__ pred, const float* __restrict__ label,
                 float* __restrict__ partials)
{
    __shared__ alignas(16) float tile[2][TILE_F];    // 18,432 B

    const int tx  = threadIdx.x;
    const int ty  = threadIdx.y;
    const int tid = tx + ty * TZ;
    const int z0  = tx * ZPT;
    const int y0  = blockIdx.x * BY;
    const int y   = y0 + ty;
    const int xs0 = blockIdx.y * XSEG;
    const int b   = blockIdx.z;
    const int bbase = b * NX * PLANE;

    // staging decomposition: flat float4-index j = r*192 + tid over
    // [tensor(2)][row(6)][z4(48)]; LDS float offset = 4*j.
    const float* sb[3];
    int lo[3];
    #pragma unroll
    for (int r = 0; r < 3; ++r) {
        const int j   = r * BLOCK_THREADS + tid;
        const int tt  = j / 288, rem = j - tt * 288;
        const int row = rem / 48, z4 = rem - row * 48;
        int grow = y0 - 1 + row;
        grow = min(max(grow, 0), NY - 1);
        sb[r] = (tt ? pred : label) + bbase + grow * NZ + z4 * 4;
        lo[r] = (tt * 6 + row) * NZ + z4 * 4;    // == 4*j
    }

    float wy[3];
    #pragma unroll
    for (int r = 0; r < 3; ++r) {
        const int yy = y + r - 1;
        wy[r] = ((unsigned)yy < (unsigned)NY) ? 1.f : 0.f;
    }
    const int   dm  = (tx == 0) ? 0 : 1;
    const int   de  = (tx == TZ - 1) ? 0 : ZPT;
    const float wzm = (tx == 0) ? 0.f : 1.f;
    const float wze = (tx == TZ - 1) ? 0.f : 1.f;

    const bool safe = (blockIdx.x >= 1) && (blockIdx.x <= NYB - 2) &&
                      (blockIdx.y >= 1) && (blockIdx.y <= NXB - 2);

    const float acc = safe
        ? march<true >(sb[0], sb[1], sb[2], lo[0], lo[1], lo[2], tile,
                       ty, z0, wy, dm, de, wzm, wze, xs0)
        : march<false>(sb[0], sb[1], sb[2], lo[0], lo[1], lo[2], tile,
                       ty, z0, wy, dm, de, wzm, wze, xs0);

    // wave (64) reduction, then block sum
    float a = acc;
    #pragma unroll
    for (int o = 32; o > 0; o >>= 1)
        a += __shfl_down(a, o, 64);

    __shared__ float wsum[BLOCK_THREADS / 64];
    if ((tid & 63) == 0) wsum[tid >> 6] = a;
    __syncthreads();
    if (tid == 0) {
        float s = 0.f;
        #pragma unroll
        for (int w = 0; w < BLOCK_THREADS / 64; ++w) s += wsum[w];
        partials[blockIdx.x + (int)gridDim.x * (blockIdx.y + (int)gridDim.y * blockIdx.z)] = s;
    }
}

__global__ __launch_bounds__(256)
void ncc_reduce(const float* __restrict__ partials, int n, float* __restrict__ out)
{
    __shared__ double sh[256];
    double s = 0.0;
    for (int i = threadIdx.x; i < n; i += 256) s += (double)partials[i];
    sh[threadIdx.x] = s;
    __syncthreads();
    for (int off = 128; off > 0; off >>= 1) {
        if ((int)threadIdx.x < off) sh[threadIdx.x] += sh[threadIdx.x + off];
        __syncthreads();
    }
    if (threadIdx.x == 0) {
        const double nvox = (double)NB * NX * NY * NZ;
        out[0] = (float)(-sh[0] / nvox);
    }
}

extern "C" void kernel_launch(void* const* d_in, const int* in_sizes, int n_in,
                              void* d_out, int out_size, void* d_ws, size_t ws_size,
                              hipStream_t stream) {
    const float* pred  = (const float*)d_in[0];
    const float* label = (const float*)d_in[1];
    float* out = (float*)d_out;
    float* partials = (float*)d_ws;

    dim3 block(TZ, BY, 1);                 // 48 x 4 = 192 threads
    dim3 grid(NYB, NXB, NB);               // 48 x 24 x 2 = 2304 blocks

    ncc_partial<<<grid, block, 0, stream>>>(pred, label, partials);
    ncc_reduce<<<1, 256, 0, stream>>>(partials, NBLK, out);
}

// Round 13
// 49.447 us; speedup vs baseline: 5.7876x; 2.2348x over previous
//
#include <hip/hip_runtime.h>

typedef float v2f __attribute__((ext_vector_type(2)));

constexpr int NX = 192, NY = 192, NZ = 192, NB = 2;
constexpr int ZPT  = 4;            // z outputs per thread
constexpr int TZ   = NZ / ZPT;     // 48
constexpr int BY   = 4;            // y rows per block
constexpr int XSEG = 4;            // x outputs per block
constexpr int BLOCK_THREADS = TZ * BY;   // 192 = 3 waves
constexpr int PLANE = NY * NZ;
constexpr int NXB = NX / XSEG;     // 48
constexpr int NYB = NY / BY;       // 48
constexpr int NBLK = NYB * NXB * NB;     // 4608 blocks
constexpr int RSTR = 196;                // padded LDS row stride (192+4):
                                         // rotates row start banks, 16B-aligned
constexpr int TILE_F = 2 * 6 * RSTR;     // 2352 floats = 9408 B per buffer

// Fold one staged x-plane from LDS (R8-proven structure, padded rows).
template<bool SAFE>
__device__ __forceinline__ void foldLDS(const float* __restrict__ buf,
    int ty, int z0, const float wy[3], int dm, int de, float wzm, float wze,
    float wx, v2f W[5][2])
{
    v2f S[5][3];
    #pragma unroll
    for (int r = 0; r < 3; ++r) {
        const float* Lt = buf + (ty + r) * RSTR;        // label row
        const float* Lp = Lt + 6 * RSTR;                // pred row
        const float4 t4 = *reinterpret_cast<const float4*>(Lt + z0);
        const float4 p4 = *reinterpret_cast<const float4*>(Lp + z0);
        const float tm = Lt[z0 - dm] * wzm, te = Lt[z0 + de] * wze;
        const float pm = Lp[z0 - dm] * wzm, pe = Lp[z0 + de] * wze;
        v2f T[3]  = { v2f{tm, t4.x}, v2f{t4.y, t4.z}, v2f{t4.w, te} };
        v2f Pv[3] = { v2f{pm, p4.x}, v2f{p4.y, p4.z}, v2f{p4.w, pe} };
        if (!SAFE) {
            const float wr = wx * wy[r];                // w in {0,1} => exact
            #pragma unroll
            for (int q = 0; q < 3; ++q) { T[q] *= wr; Pv[q] *= wr; }
        }
        #pragma unroll
        for (int q = 0; q < 3; ++q) {
            if (r == 0) {
                S[0][q] = T[q];  S[1][q] = Pv[q];
                S[2][q] = T[q] * T[q];  S[3][q] = Pv[q] * Pv[q];  S[4][q] = T[q] * Pv[q];
            } else {
                S[0][q] += T[q];  S[1][q] += Pv[q];
                S[2][q] += T[q] * T[q];  S[3][q] += Pv[q] * Pv[q];  S[4][q] += T[q] * Pv[q];
            }
        }
    }
    #pragma unroll
    for (int q = 0; q < 5; ++q) {
        const float s0 = S[q][0].x, s1 = S[q][0].y, s2 = S[q][1].x;
        const float s3 = S[q][1].y, s4 = S[q][2].x, s5 = S[q][2].y;
        const float m12 = s1 + s2, m34 = s3 + s4;
        W[q][0] = v2f{s0 + m12, m12 + s3};
        W[q][1] = v2f{s2 + m34, m34 + s5};
    }
}

__device__ __forceinline__ float epilogue4(const v2f P[5][2], const v2f Wn[5][2])
{
    constexpr float inv_vol = 1.0f / 27.0f;
    float acc = 0.f;
    #pragma unroll
    for (int h = 0; h < 2; ++h) {
        const v2f st  = P[0][h] + Wn[0][h];
        const v2f sp  = P[1][h] + Wn[1][h];
        const v2f st2 = P[2][h] + Wn[2][h];
        const v2f sp2 = P[3][h] + Wn[3][h];
        const v2f stp = P[4][h] + Wn[4][h];
        const v2f tavg = st * inv_vol;
        const v2f pavg = sp * inv_vol;
        const v2f cross = stp - pavg * st;
        const v2f tvp   = st2 - tavg * st;
        const v2f pvp   = sp2 - pavg * sp;
        const v2f cc    = cross * cross;
        #pragma unroll
        for (int c = 0; c < 2; ++c) {
            const float tvar = fmaxf(tvp[c], 0.f);
            const float pvar = fmaxf(pvp[c], 0.f);
            acc += cc[c] * __builtin_amdgcn_rcpf(fmaf(tvar, pvar, 1e-5f));
        }
    }
    return acc;
}

// March over XSEG+2 = 6 x-planes with double-buffered LDS staging.
template<bool SAFE>
__device__ __forceinline__ float march(
    const float* sb0, const float* sb1, const float* sb2,   // staging srcs (sans x)
    int lo0, int lo1, int lo2,                              // LDS float offsets
    float (*tile)[TILE_F],
    int ty, int z0, const float wy[3],
    int dm, int de, float wzm, float wze, int xs0)
{
    v2f U[5][2], V[5][2], P[5][2];
    float acc = 0.f;
    float4 G0, G1, G2;

#define XOFF(K) (SAFE ? (xs0 - 1 + (K)) * PLANE \
                      : min(max(xs0 - 1 + (K), 0), NX - 1) * PLANE)
#define WXK(K)  (SAFE ? 1.f : (((unsigned)(xs0 - 1 + (K)) < (unsigned)NX) ? 1.f : 0.f))
#define GLOAD(K) do { const int _xo = XOFF(K);                                  \
        G0 = *reinterpret_cast<const float4*>(sb0 + _xo);                       \
        G1 = *reinterpret_cast<const float4*>(sb1 + _xo);                       \
        G2 = *reinterpret_cast<const float4*>(sb2 + _xo); } while (0)
#define DSWR(K) do { float* _d = tile[(K) & 1];                                 \
        *reinterpret_cast<float4*>(_d + lo0) = G0;                              \
        *reinterpret_cast<float4*>(_d + lo1) = G1;                              \
        *reinterpret_cast<float4*>(_d + lo2) = G2; } while (0)
#define FOLD(K, WDST) foldLDS<SAFE>(tile[(K) & 1], ty, z0, wy, dm, de, wzm, wze, WXK(K), WDST)
#define PSET(A, B) do { _Pragma("unroll")                                       \
        for (int q = 0; q < 5; ++q) { _Pragma("unroll")                         \
            for (int h = 0; h < 2; ++h) P[q][h] = A[q][h] + B[q][h]; } } while (0)

    GLOAD(0); DSWR(0); __syncthreads();
    GLOAD(1); FOLD(0, U);             DSWR(1); __syncthreads();
    GLOAD(2); FOLD(1, V); PSET(U, V); DSWR(2); __syncthreads();
    GLOAD(3); FOLD(2, U); acc += epilogue4(P, U); PSET(V, U); DSWR(3); __syncthreads();
    GLOAD(4); FOLD(3, V); acc += epilogue4(P, V); PSET(U, V); DSWR(4); __syncthreads();
    GLOAD(5); FOLD(4, U); acc += epilogue4(P, U); PSET(V, U); DSWR(5); __syncthreads();
              FOLD(5, V); acc += epilogue4(P, V);

#undef XOFF
#undef WXK
#undef GLOAD
#undef DSWR
#undef FOLD
#undef PSET
    return acc;
}

__global__ __launch_bounds__(BLOCK_THREADS, 3)
void ncc_partial(const float* __restrict__ pred, const float* __restrict__ label,
                 float* __restrict__ partials)
{
    __shared__ alignas(16) float tile[2][TILE_F];    // 18,816 B

    const int tx  = threadIdx.x;
    const int ty  = threadIdx.y;
    const int tid = tx + ty * TZ;
    const int z0  = tx * ZPT;
    const int y0  = blockIdx.x * BY;
    const int y   = y0 + ty;
    const int xs0 = blockIdx.y * XSEG;
    const int b   = blockIdx.z;
    const int bbase = b * NX * PLANE;

    // staging decomposition: flat float4-index j = r*192 + tid over
    // [tensor(2)][row(6)][z4(48)]; LDS float offset uses padded row stride.
    const float* sb[3];
    int lo[3];
    #pragma unroll
    for (int r = 0; r < 3; ++r) {
        const int j   = r * BLOCK_THREADS + tid;
        const int tt  = j / 288, rem = j - tt * 288;
        const int row = rem / 48, z4 = rem - row * 48;
        int grow = y0 - 1 + row;
        grow = min(max(grow, 0), NY - 1);
        sb[r] = (tt ? pred : label) + bbase + grow * NZ + z4 * 4;
        lo[r] = (tt * 6 + row) * RSTR + z4 * 4;
    }

    float wy[3];
    #pragma unroll
    for (int r = 0; r < 3; ++r) {
        const int yy = y + r - 1;
        wy[r] = ((unsigned)yy < (unsigned)NY) ? 1.f : 0.f;
    }
    const int   dm  = (tx == 0) ? 0 : 1;
    const int   de  = (tx == TZ - 1) ? 0 : ZPT;
    const float wzm = (tx == 0) ? 0.f : 1.f;
    const float wze = (tx == TZ - 1) ? 0.f : 1.f;

    const bool safe = (blockIdx.x >= 1) && (blockIdx.x <= NYB - 2) &&
                      (blockIdx.y >= 1) && (blockIdx.y <= NXB - 2);

    const float acc = safe
        ? march<true >(sb[0], sb[1], sb[2], lo[0], lo[1], lo[2], tile,
                       ty, z0, wy, dm, de, wzm, wze, xs0)
        : march<false>(sb[0], sb[1], sb[2], lo[0], lo[1], lo[2], tile,
                       ty, z0, wy, dm, de, wzm, wze, xs0);

    // wave (64) reduction, then block sum
    float a = acc;
    #pragma unroll
    for (int o = 32; o > 0; o >>= 1)
        a += __shfl_down(a, o, 64);

    __shared__ float wsum[BLOCK_THREADS / 64];
    if ((tid & 63) == 0) wsum[tid >> 6] = a;
    __syncthreads();
    if (tid == 0) {
        float s = 0.f;
        #pragma unroll
        for (int w = 0; w < BLOCK_THREADS / 64; ++w) s += wsum[w];
        partials[blockIdx.x + (int)gridDim.x * (blockIdx.y + (int)gridDim.y * blockIdx.z)] = s;
    }
}

__global__ __launch_bounds__(256)
void ncc_reduce(const float* __restrict__ partials, int n, float* __restrict__ out)
{
    __shared__ double sh[256];
    double s = 0.0;
    for (int i = threadIdx.x; i < n; i += 256) s += (double)partials[i];
    sh[threadIdx.x] = s;
    __syncthreads();
    for (int off = 128; off > 0; off >>= 1) {
        if ((int)threadIdx.x < off) sh[threadIdx.x] += sh[threadIdx.x + off];
        __syncthreads();
    }
    if (threadIdx.x == 0) {
        const double nvox = (double)NB * NX * NY * NZ;
        out[0] = (float)(-sh[0] / nvox);
    }
}

extern "C" void kernel_launch(void* const* d_in, const int* in_sizes, int n_in,
                              void* d_out, int out_size, void* d_ws, size_t ws_size,
                              hipStream_t stream) {
    const float* pred  = (const float*)d_in[0];
    const float* label = (const float*)d_in[1];
    float* out = (float*)d_out;
    float* partials = (float*)d_ws;

    dim3 block(TZ, BY, 1);                 // 48 x 4 = 192 threads
    dim3 grid(NYB, NXB, NB);               // 48 x 48 x 2 = 4608 blocks

    ncc_partial<<<grid, block, 0, stream>>>(pred, label, partials);
    ncc_reduce<<<1, 256, 0, stream>>>(partials, NBLK, out);
}